// Round 5
// baseline (512.340 us; speedup 1.0000x reference)
//
#include <hip/hip_runtime.h>

// Forward kinematics for a serial revolute chain.
// q: [B, L] fp32, axes: [L,3], t_fix: [L,3]  ->  out: [B, L, 4, 4] fp32.
// qd is unused by the reference output.
//
// ROUND 5 = ROUND 4 RERUN (container infra failure, no data).
// PERSISTENT GRID-STRIDE waves (fill-mimicking steady state).
// Evidence r0-r3: occupancy (6 vs 16 waves/CU), compute redundancy
// (4x vs 1x), and per-instruction store contiguity (16B/64B/512B/1KB)
// are ALL individually exonerated -- results sit in a 214-252us band
// regardless, ~6x over the 33us traffic roofline, while the harness
// fill kernels sustain 6.5 TB/s on the same buffer at 10% occupancy.
// The one structural difference left vs the fill: our waves were all
// short-lived (cold q load -> one element batch -> 24 stores -> vmcnt
// drain at endpgm), never reaching store steady-state. This round:
// long-lived waves, grid-stride over elements, next element's q
// prefetched into registers under the current element's compute, so
// stores stream back-to-back like the fill's.
//
//  - r1's compute split (4 lanes/element, lane owns one output row;
//    row i of R_parent@J depends only on row i of R_parent).
//  - 512 blocks = 2048 waves = 2 waves/SIMD; each 4-lane group handles
//    nb/32768 = 4 elements.
//  - s_lnk rows padded to 16 words: exactly 3 broadcast ds_read_b128
//    per link (r1 had 48B rows -> scalarized ds reads + lgkmcnt stalls).
//  - Plain stores (not nontemporal): r1 (plain) beat r3 (nt).

typedef float v4 __attribute__((ext_vector_type(4)));

constexpr int L = 24;
constexpr int BLOCKS = 512;
constexpr int NGROUPS = BLOCKS * 64;   // 4-lane groups in the grid

__global__ __launch_bounds__(256, 4) void fk_kernel(
    const float* __restrict__ q,
    const float* __restrict__ axes,
    const float* __restrict__ tfix,
    float* __restrict__ out,
    int nb)
{
    // {ax,ay,az,fx, fy,fz,xx,yy, zz,xy,xz,yz, pad[4]} -- 64B rows.
    __shared__ __align__(16) float s_lnk[L][16];

    if (threadIdx.x < L) {
        const int l = threadIdx.x;
        float ax = axes[l*3+0], ay = axes[l*3+1], az = axes[l*3+2];
        float inv = rsqrtf(ax*ax + ay*ay + az*az);
        ax *= inv; ay *= inv; az *= inv;
        s_lnk[l][0] = ax;            s_lnk[l][1] = ay;            s_lnk[l][2] = az;
        s_lnk[l][3] = tfix[l*3+0];   s_lnk[l][4] = tfix[l*3+1];   s_lnk[l][5] = tfix[l*3+2];
        s_lnk[l][6] = ax*ax;         s_lnk[l][7] = ay*ay;
        s_lnk[l][8] = az*az;         s_lnk[l][9] = ax*ay;
        s_lnk[l][10] = ax*az;        s_lnk[l][11] = ay*az;
        s_lnk[l][12] = 0.f; s_lnk[l][13] = 0.f; s_lnk[l][14] = 0.f; s_lnk[l][15] = 0.f;
    }
    __syncthreads();

    const int tid = blockIdx.x * 256 + threadIdx.x;
    const int gid = tid >> 2;      // 4-lane group id == first element id
    const int r   = tid & 3;       // output row owned by this lane

    int b = gid;
    if (b >= nb) return;

    const v4* q4 = (const v4*)q;   // element b's angles at q4[b*6 .. b*6+5]

    // Prime the software pipeline: q of the first element.
    v4 nq0 = q4[(size_t)b * 6 + 0];
    v4 nq1 = q4[(size_t)b * 6 + 1];
    v4 nq2 = q4[(size_t)b * 6 + 2];
    v4 nq3 = q4[(size_t)b * 6 + 3];
    v4 nq4 = q4[(size_t)b * 6 + 4];
    v4 nq5 = q4[(size_t)b * 6 + 5];

    while (b < nb) {
        // Current element's angles (keeps nq free for the prefetch).
        float qv[L];
        qv[0]=nq0.x; qv[1]=nq0.y; qv[2]=nq0.z; qv[3]=nq0.w;
        qv[4]=nq1.x; qv[5]=nq1.y; qv[6]=nq1.z; qv[7]=nq1.w;
        qv[8]=nq2.x; qv[9]=nq2.y; qv[10]=nq2.z; qv[11]=nq2.w;
        qv[12]=nq3.x; qv[13]=nq3.y; qv[14]=nq3.z; qv[15]=nq3.w;
        qv[16]=nq4.x; qv[17]=nq4.y; qv[18]=nq4.z; qv[19]=nq4.w;
        qv[20]=nq5.x; qv[21]=nq5.y; qv[22]=nq5.z; qv[23]=nq5.w;

        // Prefetch next element's angles; latency hides under the 24-link
        // compute below. (Redundant across the 4-lane group; L1 broadcast
        // absorbs it -- exonerated in r1.)
        const int bn = b + NGROUPS;
        if (bn < nb) {
            nq0 = q4[(size_t)bn * 6 + 0];
            nq1 = q4[(size_t)bn * 6 + 1];
            nq2 = q4[(size_t)bn * 6 + 2];
            nq3 = q4[(size_t)bn * 6 + 3];
            nq4 = q4[(size_t)bn * 6 + 4];
            nq5 = q4[(size_t)bn * 6 + 5];
        }

        // Row r of the identity pose; row 3 -> (0,0,0,1), a fixed point
        // of the recurrence (Ra=Rb=Rc=0).
        float Ra = (r == 0) ? 1.f : 0.f;
        float Rb = (r == 1) ? 1.f : 0.f;
        float Rc = (r == 2) ? 1.f : 0.f;
        float t  = (r == 3) ? 1.f : 0.f;

        v4* orow = (v4*)out + (size_t)b * (4 * L) + r;   // + l*4 per link

        #pragma unroll
        for (int l = 0; l < L; ++l) {
            const v4 c0 = *(const v4*)&s_lnk[l][0];
            const v4 c1 = *(const v4*)&s_lnk[l][4];
            const v4 c2 = *(const v4*)&s_lnk[l][8];
            const float ax = c0.x, ay = c0.y, az = c0.z, fx = c0.w;
            const float fy = c1.x, fz = c1.y, xx = c1.z, yy = c1.w;
            const float zz = c2.x, xy = c2.y, xz = c2.z, yz = c2.w;

            float s, c;
            __sincosf(qv[l], &s, &c);
            const float omc = 1.0f - c;

            // Rodrigues for unit axis a: J = c*I + s*K + (1-c) a a^T
            const float J00 = fmaf(omc, xx, c);
            const float J11 = fmaf(omc, yy, c);
            const float J22 = fmaf(omc, zz, c);
            const float oxy = omc * xy, oxz = omc * xz, oyz = omc * yz;
            const float sx = s * ax, sy = s * ay, sz = s * az;
            const float J01 = oxy - sz, J10 = oxy + sz;
            const float J02 = oxz + sy, J20 = oxz - sy;
            const float J12 = oyz - sx, J21 = oyz + sx;

            // translation uses the PARENT rotation row (pre-update)
            t = fmaf(Ra, fx, fmaf(Rb, fy, fmaf(Rc, fz, t)));

            // row r of R_child = row r of R_parent @ J
            const float na  = fmaf(Ra, J00, fmaf(Rb, J10, Rc * J20));
            const float nb_ = fmaf(Ra, J01, fmaf(Rb, J11, Rc * J21));
            const float nc  = fmaf(Ra, J02, fmaf(Rb, J12, Rc * J22));
            Ra = na; Rb = nb_; Rc = nc;

            // 4-lane group writes 64B contiguous at out[b][l][r][0..3];
            // a wave-instr covers 16 consecutive elements' link-l rows.
            orow[l * 4] = v4{Ra, Rb, Rc, t};
        }

        b = bn;
    }
}

extern "C" void kernel_launch(void* const* d_in, const int* in_sizes, int n_in,
                              void* d_out, int out_size, void* d_ws, size_t ws_size,
                              hipStream_t stream) {
    const float* q    = (const float*)d_in[0];
    // d_in[1] = qd: unused by the reference output
    const float* axes = (const float*)d_in[2];
    const float* tfix = (const float*)d_in[3];
    float* out = (float*)d_out;

    const int nb = in_sizes[0] / L;                 // 131072
    fk_kernel<<<BLOCKS, 256, 0, stream>>>(q, axes, tfix, out, nb);
}

// Round 6
// 243.661 us; speedup vs baseline: 2.1027x; 2.1027x over previous
//
#include <hip/hip_runtime.h>

// Forward kinematics for a serial revolute chain.
// q: [B, L] fp32, axes: [L,3], t_fix: [L,3]  ->  out: [B, L, 4, 4] fp32.
// qd is unused by the reference output.
//
// ROUND 6: revert to the r1 structure (best measured) + targeted fixes.
// r5's counters (first direct fk_kernel visibility) recalibrated everything:
//   - dur_us carries ~166us of harness reset traffic per iteration; the
//     kernels' true times were r0=56, r1=48, r2=86, r3=58, r5=346 us.
//   - r1 was already at 214MB/48us = 4.5 TB/s (~70% of the 6.5 TB/s the
//     fills demonstrate). The structural perturbation rounds were moving
//     a 48us term inside a 214us measurement.
//   - r5's blowup: VGPR_Count=64 (compiler pinned to the 64-reg occupancy
//     step) with ~100 regs of live state -> scratch spills -> FETCH 461MB /
//     WRITE 444MB (2.2x amplification), plus >63 outstanding VMEM ops
//     forcing partial store drains. Persistence never got a clean test.
//
// This round, on r1's proven skeleton (one element per 4-lane group, lane
// owns one output row, direct stores, full grid, short waves):
//   1. NONTEMPORAL direct stores -- the one untested axis on this path
//      (r0/r3 used nt only behind LDS staging). Tests whether r1's 30%
//      gap to fill BW is L2 allocation/RMW overhead on 64B partial-line
//      streaming writes.
//   2. s_lnk __align__(16), 64B rows -> guaranteed 3x broadcast
//      ds_read_b128 per link.
//   3. q kept in 6 v4 registers, components indexed at compile time
//      (no float[24] copy) -> ~60 VGPR, no spill risk at the 64-reg step.

typedef float v4 __attribute__((ext_vector_type(4)));

constexpr int L = 24;

__global__ __launch_bounds__(256, 4) void fk_kernel(
    const float* __restrict__ q,
    const float* __restrict__ axes,
    const float* __restrict__ tfix,
    float* __restrict__ out,
    int nb)
{
    // {ax,ay,az,fx, fy,fz,xx,yy, zz,xy,xz,yz, pad[4]} -- 64B rows.
    __shared__ __align__(16) float s_lnk[L][16];

    if (threadIdx.x < L) {
        const int l = threadIdx.x;
        float ax = axes[l*3+0], ay = axes[l*3+1], az = axes[l*3+2];
        float inv = rsqrtf(ax*ax + ay*ay + az*az);
        ax *= inv; ay *= inv; az *= inv;
        s_lnk[l][0] = ax;            s_lnk[l][1] = ay;            s_lnk[l][2] = az;
        s_lnk[l][3] = tfix[l*3+0];   s_lnk[l][4] = tfix[l*3+1];   s_lnk[l][5] = tfix[l*3+2];
        s_lnk[l][6] = ax*ax;         s_lnk[l][7] = ay*ay;
        s_lnk[l][8] = az*az;         s_lnk[l][9] = ax*ay;
        s_lnk[l][10] = ax*az;        s_lnk[l][11] = ay*az;
        s_lnk[l][12] = 0.f; s_lnk[l][13] = 0.f; s_lnk[l][14] = 0.f; s_lnk[l][15] = 0.f;
    }
    __syncthreads();

    const int tid = blockIdx.x * 256 + threadIdx.x;
    const int b = tid >> 2;   // batch element
    const int r = tid & 3;    // output row owned by this lane
    if (b >= nb) return;

    // 24 angles in 6 v4 registers; components extracted with
    // compile-time indices inside the unrolled loop (no array copy).
    // Redundant across the 4-lane group; same-address lanes coalesce.
    v4 nq[6];
    {
        const v4* q4 = (const v4*)(q + (size_t)b * L);
        #pragma unroll
        for (int i = 0; i < 6; ++i) nq[i] = q4[i];
    }

    // Row r of the identity pose; row 3 -> (0,0,0,1), a fixed point of
    // the recurrence (Ra=Rb=Rc=0).
    float Ra = (r == 0) ? 1.f : 0.f;
    float Rb = (r == 1) ? 1.f : 0.f;
    float Rc = (r == 2) ? 1.f : 0.f;
    float t  = (r == 3) ? 1.f : 0.f;

    v4* orow = (v4*)out + (size_t)b * (4 * L) + r;   // + l*4 per link

    #pragma unroll
    for (int l = 0; l < L; ++l) {
        const v4 c0 = *(const v4*)&s_lnk[l][0];
        const v4 c1 = *(const v4*)&s_lnk[l][4];
        const v4 c2 = *(const v4*)&s_lnk[l][8];
        const float ax = c0.x, ay = c0.y, az = c0.z, fx = c0.w;
        const float fy = c1.x, fz = c1.y, xx = c1.z, yy = c1.w;
        const float zz = c2.x, xy = c2.y, xz = c2.z, yz = c2.w;

        float s, c;
        __sincosf(nq[l >> 2][l & 3], &s, &c);
        const float omc = 1.0f - c;

        // Rodrigues for unit axis a: J = c*I + s*K + (1-c) a a^T
        const float J00 = fmaf(omc, xx, c);
        const float J11 = fmaf(omc, yy, c);
        const float J22 = fmaf(omc, zz, c);
        const float oxy = omc * xy, oxz = omc * xz, oyz = omc * yz;
        const float sx = s * ax, sy = s * ay, sz = s * az;
        const float J01 = oxy - sz, J10 = oxy + sz;
        const float J02 = oxz + sy, J20 = oxz - sy;
        const float J12 = oyz - sx, J21 = oyz + sx;

        // translation uses the PARENT rotation row (pre-update)
        t = fmaf(Ra, fx, fmaf(Rb, fy, fmaf(Rc, fz, t)));

        // row r of R_child = row r of R_parent @ J
        const float na  = fmaf(Ra, J00, fmaf(Rb, J10, Rc * J20));
        const float nb_ = fmaf(Ra, J01, fmaf(Rb, J11, Rc * J21));
        const float nc  = fmaf(Ra, J02, fmaf(Rb, J12, Rc * J22));
        Ra = na; Rb = nb_; Rc = nc;

        // 4-lane group writes 64B contiguous at out[b][l][r][0..3];
        // nontemporal: output is write-once, never re-read.
        __builtin_nontemporal_store(v4{Ra, Rb, Rc, t}, &orow[l * 4]);
    }
}

extern "C" void kernel_launch(void* const* d_in, const int* in_sizes, int n_in,
                              void* d_out, int out_size, void* d_ws, size_t ws_size,
                              hipStream_t stream) {
    const float* q    = (const float*)d_in[0];
    // d_in[1] = qd: unused by the reference output
    const float* axes = (const float*)d_in[2];
    const float* tfix = (const float*)d_in[3];
    float* out = (float*)d_out;

    const int nb = in_sizes[0] / L;                 // 131072
    const long long nthreads = (long long)nb * 4;   // 4 lanes per element
    const int grid = (int)((nthreads + 255) / 256);
    fk_kernel<<<grid, 256, 0, stream>>>(q, axes, tfix, out, nb);
}

// Round 7
// 215.198 us; speedup vs baseline: 2.3808x; 1.1323x over previous
//
#include <hip/hip_runtime.h>

// Forward kinematics for a serial revolute chain.
// q: [B, L] fp32, axes: [L,3], t_fix: [L,3]  ->  out: [B, L, 4, 4] fp32.
// qd is unused by the reference output.
//
// ROUND 7: r6 minus nontemporal = r1's winning skeleton + clean fixes.
// Final axis scorecard (fk-share times after subtracting the ~166us of
// harness reset traffic r5's direct counters exposed):
//   r0 staged-1KB lowocc: 56us | r1 direct-64B highocc: 48us (BEST)
//   r2 1-thread/elem:     86us | r3 staged-512B highocc: 58us
//   r5 persistent(spill):346us | r6 direct-64B + nt:     ~78us
// nt on the direct path REGRESSED (+30us): it defeats L2 merging of the
// four neighboring 64B half-line writes -> partial-line HBM writebacks
// with RMW. Plain stores + 64B group runs is the measured-best write
// path; staging, persistence, nt, 1-thread compute all individually
// refuted. r1's one unfixed flaw was 48B s_lnk rows (scalarized
// ds_read2_b32 chains + per-link lgkmcnt stalls); kept fixed here.
//
//  - 4 lanes/element, lane owns one output row (row i of R_parent@J
//    depends only on row i of R_parent).
//  - s_lnk __align__(16), 64B rows -> exactly 3 broadcast ds_read_b128
//    per link.
//  - q in 6 v4 regs, compile-time component indexing (no array copy).
//  - Plain 16B stores; 4-lane group covers 64B contiguous; consecutive
//    links from the group fill adjacent 64B halves of 128B lines
//    back-to-back, L2 merges before writeback.

typedef float v4 __attribute__((ext_vector_type(4)));

constexpr int L = 24;

__global__ __launch_bounds__(256, 4) void fk_kernel(
    const float* __restrict__ q,
    const float* __restrict__ axes,
    const float* __restrict__ tfix,
    float* __restrict__ out,
    int nb)
{
    // {ax,ay,az,fx, fy,fz,xx,yy, zz,xy,xz,yz, pad[4]} -- 64B rows.
    __shared__ __align__(16) float s_lnk[L][16];

    if (threadIdx.x < L) {
        const int l = threadIdx.x;
        float ax = axes[l*3+0], ay = axes[l*3+1], az = axes[l*3+2];
        float inv = rsqrtf(ax*ax + ay*ay + az*az);
        ax *= inv; ay *= inv; az *= inv;
        s_lnk[l][0] = ax;            s_lnk[l][1] = ay;            s_lnk[l][2] = az;
        s_lnk[l][3] = tfix[l*3+0];   s_lnk[l][4] = tfix[l*3+1];   s_lnk[l][5] = tfix[l*3+2];
        s_lnk[l][6] = ax*ax;         s_lnk[l][7] = ay*ay;
        s_lnk[l][8] = az*az;         s_lnk[l][9] = ax*ay;
        s_lnk[l][10] = ax*az;        s_lnk[l][11] = ay*az;
        s_lnk[l][12] = 0.f; s_lnk[l][13] = 0.f; s_lnk[l][14] = 0.f; s_lnk[l][15] = 0.f;
    }
    __syncthreads();

    const int tid = blockIdx.x * 256 + threadIdx.x;
    const int b = tid >> 2;   // batch element
    const int r = tid & 3;    // output row owned by this lane
    if (b >= nb) return;

    // 24 angles in 6 v4 registers; components extracted with
    // compile-time indices inside the unrolled loop (no array copy).
    // Redundant across the 4-lane group; L1 broadcast absorbs it.
    v4 nq[6];
    {
        const v4* q4 = (const v4*)(q + (size_t)b * L);
        #pragma unroll
        for (int i = 0; i < 6; ++i) nq[i] = q4[i];
    }

    // Row r of the identity pose; row 3 -> (0,0,0,1), a fixed point of
    // the recurrence (Ra=Rb=Rc=0).
    float Ra = (r == 0) ? 1.f : 0.f;
    float Rb = (r == 1) ? 1.f : 0.f;
    float Rc = (r == 2) ? 1.f : 0.f;
    float t  = (r == 3) ? 1.f : 0.f;

    v4* orow = (v4*)out + (size_t)b * (4 * L) + r;   // + l*4 per link

    #pragma unroll
    for (int l = 0; l < L; ++l) {
        const v4 c0 = *(const v4*)&s_lnk[l][0];
        const v4 c1 = *(const v4*)&s_lnk[l][4];
        const v4 c2 = *(const v4*)&s_lnk[l][8];
        const float ax = c0.x, ay = c0.y, az = c0.z, fx = c0.w;
        const float fy = c1.x, fz = c1.y, xx = c1.z, yy = c1.w;
        const float zz = c2.x, xy = c2.y, xz = c2.z, yz = c2.w;

        float s, c;
        __sincosf(nq[l >> 2][l & 3], &s, &c);
        const float omc = 1.0f - c;

        // Rodrigues for unit axis a: J = c*I + s*K + (1-c) a a^T
        const float J00 = fmaf(omc, xx, c);
        const float J11 = fmaf(omc, yy, c);
        const float J22 = fmaf(omc, zz, c);
        const float oxy = omc * xy, oxz = omc * xz, oyz = omc * yz;
        const float sx = s * ax, sy = s * ay, sz = s * az;
        const float J01 = oxy - sz, J10 = oxy + sz;
        const float J02 = oxz + sy, J20 = oxz - sy;
        const float J12 = oyz - sx, J21 = oyz + sx;

        // translation uses the PARENT rotation row (pre-update)
        t = fmaf(Ra, fx, fmaf(Rb, fy, fmaf(Rc, fz, t)));

        // row r of R_child = row r of R_parent @ J
        const float na  = fmaf(Ra, J00, fmaf(Rb, J10, Rc * J20));
        const float nb_ = fmaf(Ra, J01, fmaf(Rb, J11, Rc * J21));
        const float nc  = fmaf(Ra, J02, fmaf(Rb, J12, Rc * J22));
        Ra = na; Rb = nb_; Rc = nc;

        // 4-lane group writes 64B contiguous at out[b][l][r][0..3].
        orow[l * 4] = v4{Ra, Rb, Rc, t};
    }
}

extern "C" void kernel_launch(void* const* d_in, const int* in_sizes, int n_in,
                              void* d_out, int out_size, void* d_ws, size_t ws_size,
                              hipStream_t stream) {
    const float* q    = (const float*)d_in[0];
    // d_in[1] = qd: unused by the reference output
    const float* axes = (const float*)d_in[2];
    const float* tfix = (const float*)d_in[3];
    float* out = (float*)d_out;

    const int nb = in_sizes[0] / L;                 // 131072
    const long long nthreads = (long long)nb * 4;   // 4 lanes per element
    const int grid = (int)((nthreads + 255) / 256);
    fk_kernel<<<grid, 256, 0, stream>>>(q, axes, tfix, out, nb);
}